// Round 1
// baseline (812.527 us; speedup 1.0000x reference)
//
#include <hip/hip_runtime.h>
#include <cmath>

#define HH 512
#define WW 512
#define NB 8
#define TH 32
#define TW 64
#define USH (TH+4)   // 36  rows of u_t stage (halo 2)
#define USW (TW+4)   // 68  cols
#define HSH (TH+4)   // 36  rows of horizontal-sum buffer
#define HSW (TW+2)   // 66  cols (halo 1)
#define VH  (TH+2)   // 34  rows of v = 1/u1 (halo 1)
#define VW  (TW+2)   // 66  cols
#define H2W TW       // 64  cols of second horizontal-sum
#define LOG9 2.1972245773362196f
#define EPS  0.05f

// init: u0 = exp(-img/eps), skel = 0   (exactly one float4 per thread)
__global__ __launch_bounds__(256)
void sk_init(const float4* __restrict__ img, float4* __restrict__ u0,
             float4* __restrict__ skel) {
    int i = blockIdx.x * 256 + threadIdx.x;
    float4 x = img[i];
    float4 u;
    u.x = expf(-(x.x / EPS));
    u.y = expf(-(x.y / EPS));
    u.z = expf(-(x.z / EPS));
    u.w = expf(-(x.w / EPS));
    u0[i] = u;
    skel[i] = make_float4(0.f, 0.f, 0.f, 0.f);
}

// One fused iteration:
//   u_out = boxavg3x3(u_in)          (erode chain, exp-domain)
//   v     = 1/u_out                   (dilate's exp input)
//   d     = clip(EPS*(log(boxsum3x3(v)) - LOG9), 0, 1)
//   skel += relu(e_t - d),  e_t = img (FIRST) or -EPS*log(u_in)
// Edge-replicate padding via clamped indexing; halo u1 entries are computed
// AT the clamped global position so the second conv's replicate-pad is exact.
template<bool FIRST>
__global__ __launch_bounds__(256)
void sk_iter(const float* __restrict__ u_in, const float* __restrict__ img,
             float* __restrict__ u_out, float* __restrict__ skel) {
    __shared__ float us[USH * USW];   // u_t tile + halo2           (9.8 KB)
    __shared__ float hs[HSH * HSW];   // h-sums, reused for 2nd conv (9.5 KB)
    __shared__ float vv[VH * VW];     // v = 1/u1, halo1            (9.0 KB)

    const int b   = blockIdx.z;
    const int r0  = blockIdx.y * TH;
    const int c0  = blockIdx.x * TW;
    const int tid = threadIdx.x;
    const float* ub = u_in + (size_t)b * (HH * WW);

    // phase 1: stage u_t with replicate clamp
    for (int i = tid; i < USH * USW; i += 256) {
        int lr = i / USW, lc = i - lr * USW;
        int gr = min(max(r0 - 2 + lr, 0), HH - 1);
        int gc = min(max(c0 - 2 + lc, 0), WW - 1);
        us[i] = ub[gr * WW + gc];
    }
    __syncthreads();

    // phase 2: horizontal 3-sums of u_t
    for (int i = tid; i < HSH * HSW; i += 256) {
        int lr = i / HSW, lc = i - lr * HSW;
        const float* p = us + lr * USW + lc;
        hs[i] = p[0] + p[1] + p[2];
    }
    __syncthreads();

    // phase 3: u1 = vertical 3-sum / 9 on halo-1 region (computed at the
    // CLAMPED global position for out-of-image halo entries), v = 1/u1,
    // write interior u1 to u_out
    float* uob = u_out + (size_t)b * (HH * WW);
    for (int i = tid; i < VH * VW; i += 256) {
        int lr = i / VW, lc = i - lr * VW;
        int gr = r0 - 1 + lr, gc = c0 - 1 + lc;
        int grc = min(max(gr, 0), HH - 1);
        int gcc = min(max(gc, 0), WW - 1);
        int hr = grc - r0 + 2;   // hs row index of clamped center
        int hc = gcc - c0 + 1;   // hs col index of clamped center
        float s = hs[(hr - 1) * HSW + hc] + hs[hr * HSW + hc] + hs[(hr + 1) * HSW + hc];
        float u1 = s * (1.0f / 9.0f);
        vv[i] = 1.0f / u1;
        if (lr >= 1 && lr < VH - 1 && lc >= 1 && lc < VW - 1)
            uob[gr * WW + gc] = u1;
    }
    __syncthreads();

    // phase 4: horizontal 3-sums of v (reuse hs buffer, stride H2W)
    for (int i = tid; i < VH * H2W; i += 256) {
        int lr = i / H2W, lc = i - lr * H2W;
        const float* p = vv + lr * VW + lc;
        hs[i] = p[0] + p[1] + p[2];
    }
    __syncthreads();

    // phase 5: dilate vertical sum, log, clip, skel accumulate
    const float* eb = img + (size_t)b * (HH * WW);
    float* sb = skel + (size_t)b * (HH * WW);
    for (int i = tid; i < TH * TW; i += 256) {
        int tr = i / TW, tc = i - tr * TW;
        float sd = hs[tr * H2W + tc] + hs[(tr + 1) * H2W + tc] + hs[(tr + 2) * H2W + tc];
        float d = EPS * (logf(sd) - LOG9);
        d = fminf(fmaxf(d, 0.0f), 1.0f);
        int gr = r0 + tr, gc = c0 + tc;
        float e;
        if (FIRST) e = eb[gr * WW + gc];
        else       e = -EPS * logf(us[(tr + 2) * USW + (tc + 2)]);
        float r = e - d;
        if (r > 0.0f) sb[gr * WW + gc] += r;
    }
}

extern "C" void kernel_launch(void* const* d_in, const int* in_sizes, int n_in,
                              void* d_out, int out_size, void* d_ws, size_t ws_size,
                              hipStream_t stream) {
    const float* img = (const float*)d_in[0];
    float* skel = (float*)d_out;
    const size_t N = (size_t)NB * HH * WW;   // 2,097,152
    float* ua = (float*)d_ws;
    float* ub = ua + N;                       // needs 16.8 MB of ws

    sk_init<<<dim3((unsigned)(N / 4 / 256)), 256, 0, stream>>>(
        (const float4*)img, (float4*)ua, (float4*)skel);

    dim3 grid(WW / TW, HH / TH, NB);          // (8, 16, 8) = 1024 blocks
    float* uin = ua;
    float* uout = ub;
    for (int t = 0; t < 51; ++t) {
        if (t == 0)
            sk_iter<true><<<grid, 256, 0, stream>>>(uin, img, uout, skel);
        else
            sk_iter<false><<<grid, 256, 0, stream>>>(uin, img, uout, skel);
        float* tmp = uin; uin = uout; uout = tmp;
    }
}

// Round 3
// 477.534 us; speedup vs baseline: 1.7015x; 1.7015x over previous
//
#include <hip/hip_runtime.h>

#define HH 512
#define WW 512
#define NB 8
#define TH 32
#define TW 64

__device__ __forceinline__ float rcp_f(float x)  { return __builtin_amdgcn_rcpf(x); }
__device__ __forceinline__ float log2_f(float x) { return __builtin_amdgcn_logf(x); }
__device__ __forceinline__ float exp2_f(float x) { return __builtin_amdgcn_exp2f(x); }

// d = EPS*(ln(s) - ln 9) = C1*(log2 s - LOG2_9);  e = -C1*log2(u);  u0 = exp2(img*NEG_INV)
#define C1      0.034657359027997264f   /* EPS*ln2            */
#define LOG2_9  3.1699250014423126f
#define NEG_INV -28.853900817779268f    /* -1/(EPS*ln2)       */

// One fused soft-morphology step in LDS.
//   IN : u_k  at halo A   (region (TH+2A) x (TW+2A), stride TW+2A)
//   OUT: u_{k+1} at halo A-1 (stride TW+2A-2), halo entries computed AT the
//        clamped global position so replicate-pad stays exact recursively.
//   H  : scratch, reused as h-sum buffer then as HV (rcp h-sum) buffer.
//   sk : 8 per-thread skel accumulators (pixel j*256+tid of the 32x64 tile).
template<int A, bool LAST, bool E_IMG, bool WRITEU>
__device__ __forceinline__ void one_step(
    float* __restrict__ IN, float* __restrict__ OUT, float* __restrict__ H,
    int r0, int c0, int tid,
    float* __restrict__ uog, const float* __restrict__ imgb, float (&sk)[8])
{
    constexpr int SIN  = TW + 2*A;      // IN stride
    constexpr int RIN  = TH + 2*A;      // IN rows
    constexpr int B_   = A - 1;         // OUT halo
    constexpr int SOUT = TW + 2*B_;     // OUT stride == H stride == SIN-2
    constexpr int ROUT = TH + 2*B_;

    // phase A: horizontal 3-sums of IN -> H  (RIN x SOUT)
    for (int i = tid; i < RIN*SOUT; i += 256) {
        int r = i / SOUT, c = i - r*SOUT;
        const float* p = IN + r*SIN + c;
        H[i] = p[0] + p[1] + p[2];
    }
    __syncthreads();

    // phase B: vertical 3-sum /9 at CLAMPED centers -> OUT (ROUT x SOUT)
    for (int i = tid; i < ROUT*SOUT; i += 256) {
        int r = i / SOUT, c = i - r*SOUT;
        int gr = r0 - B_ + r, gc = c0 - B_ + c;
        int rcl = min(max(gr, 0), HH-1) - (r0 - B_);
        int ccl = min(max(gc, 0), WW-1) - (c0 - B_);
        const float* h = H + rcl*SOUT + ccl;
        float u1 = (h[0] + h[SOUT] + h[2*SOUT]) * (1.0f/9.0f);
        OUT[i] = u1;
        if constexpr (LAST && WRITEU) {
            if (r >= B_ && r < B_+TH && c >= B_ && c < B_+TW)
                uog[gr*WW + gc] = u1;
        }
    }
    __syncthreads();

    // phase C: HV[r][c] = sum_j rcp(OUT[B_-1+r][B_-1+c+j])  ((TH+2) x TW) -> H
    for (int i = tid; i < (TH+2)*TW; i += 256) {
        int r = i >> 6, c = i & (TW-1);
        const float* p = OUT + (B_-1+r)*SOUT + (B_-1+c);
        H[i] = rcp_f(p[0]) + rcp_f(p[1]) + rcp_f(p[2]);
    }
    __syncthreads();

    // phase D: dilate v-sum, log, clip, skel accumulate (TH x TW, 8 px/thread)
    #pragma unroll
    for (int j = 0; j < 8; ++j) {
        int idx = j*256 + tid;
        int tr = idx >> 6, tc = idx & (TW-1);
        float sd = H[tr*TW+tc] + H[(tr+1)*TW+tc] + H[(tr+2)*TW+tc];
        float d = C1 * (log2_f(sd) - LOG2_9);
        d = fminf(fmaxf(d, 0.0f), 1.0f);
        float e;
        if constexpr (E_IMG) e = imgb[(r0+tr)*WW + (c0+tc)];
        else                 e = -C1 * log2_f(IN[(A+tr)*SIN + (A+tc)]);
        sk[j] += fmaxf(e - d, 0.0f);
    }
    __syncthreads();
}

template<int A, int REMAIN, bool E_IMG, bool WRITEU>
struct Chain {
    static __device__ __forceinline__ void run(
        float* IN, float* OUT, float* H, int r0, int c0, int tid,
        float* uog, const float* imgb, float (&sk)[8])
    {
        one_step<A, (REMAIN==1), E_IMG, WRITEU>(IN, OUT, H, r0, c0, tid, uog, imgb, sk);
        if constexpr (REMAIN > 1)
            Chain<A-1, REMAIN-1, false, WRITEU>::run(OUT, IN, H, r0, c0, tid, uog, imgb, sk);
    }
};

// NSTEP fused iterations. FIRST folds u0 = exp2(img*NEG_INV) into the stage
// and WRITES skel (poisoned output); later kernels accumulate.
template<bool FIRST, int NSTEP, bool WRITEU>
__global__ __launch_bounds__(256)
void sk_fused(const float* __restrict__ u_in, const float* __restrict__ img,
              float* __restrict__ u_out, float* __restrict__ skel)
{
    constexpr int A0 = NSTEP + 1;
    constexpr int S0 = TW + 2*A0;
    constexpr int R0 = TH + 2*A0;
    __shared__ float bufA[(TH+12)*(TW+12)];   // 44*76 = 13.4 KB
    __shared__ float bufB[(TH+12)*(TW+12)];   // 13.4 KB
    __shared__ float bufH[(TH+12)*(TW+10)];   // 44*74 = 13.0 KB  (39.8 KB total -> 4 blk/CU)

    const int b   = blockIdx.z;
    const int r0  = blockIdx.y * TH;
    const int c0  = blockIdx.x * TW;
    const int tid = threadIdx.x;
    const size_t boff = (size_t)b * (HH*WW);
    const float* imgb = img + boff;
    float* uog = u_out + boff;
    float* skb = skel + boff;

    // stage u at halo A0 (clamped replicate)
    for (int i = tid; i < R0*S0; i += 256) {
        int r = i / S0, c = i - r*S0;
        int gr = min(max(r0 - A0 + r, 0), HH-1);
        int gc = min(max(c0 - A0 + c, 0), WW-1);
        if constexpr (FIRST) bufA[i] = exp2_f(imgb[gr*WW+gc] * NEG_INV);
        else                 bufA[i] = (u_in + boff)[gr*WW+gc];
    }
    __syncthreads();

    float sk[8];
    #pragma unroll
    for (int j = 0; j < 8; ++j) sk[j] = 0.0f;

    Chain<A0, NSTEP, FIRST, WRITEU>::run(bufA, bufB, bufH, r0, c0, tid, uog, imgb, sk);

    #pragma unroll
    for (int j = 0; j < 8; ++j) {
        int idx = j*256 + tid;
        int tr = idx >> 6, tc = idx & (TW-1);
        float* sp = skb + (r0+tr)*WW + (c0+tc);
        if constexpr (FIRST) *sp = sk[j];
        else                 *sp += sk[j];
    }
}

extern "C" void kernel_launch(void* const* d_in, const int* in_sizes, int n_in,
                              void* d_out, int out_size, void* d_ws, size_t ws_size,
                              hipStream_t stream) {
    const float* img = (const float*)d_in[0];
    float* skel = (float*)d_out;
    const size_t N = (size_t)NB * HH * WW;
    float* ua = (float*)d_ws;
    float* ub = ua + N;                       // 16.8 MB of ws used

    dim3 grid(WW/TW, HH/TH, NB);              // (8,16,8) = 1024 blocks

    // steps 0..4 (e_0 = img exactly), writes u5
    sk_fused<true, 5, true><<<grid, 256, 0, stream>>>(nullptr, img, ua, skel);

    // steps 5..49 in 9 kernels of 5
    float* uin = ua; float* uout = ub;
    for (int t = 0; t < 9; ++t) {
        sk_fused<false, 5, true><<<grid, 256, 0, stream>>>(uin, img, uout, skel);
        float* tmp = uin; uin = uout; uout = tmp;
    }

    // step 50 (no u write needed)
    sk_fused<false, 1, false><<<grid, 256, 0, stream>>>(uin, img, uout, skel);
}

// Round 8
// 423.017 us; speedup vs baseline: 1.9208x; 1.1289x over previous
//
#include <hip/hip_runtime.h>

#define HH 512
#define WW 512
#define NB 8
#define TH 32
#define TW 64
#define ST 80      // LDS row stride in floats (16B-aligned rows)
#define RB 48      // LDS rows per buffer
#define RO 8       // buffer row 8  <-> tile row r0
#define CO 8       // buffer col 8  <-> tile col c0

__device__ __forceinline__ float rcp_f(float x)  { return __builtin_amdgcn_rcpf(x); }
__device__ __forceinline__ float log2_f(float x) { return __builtin_amdgcn_logf(x); }
__device__ __forceinline__ float exp2_f(float x) { return __builtin_amdgcn_exp2f(x); }

#define C1      0.034657359027997264f   /* EPS*ln2       */
#define LOG2_9  3.1699250014423126f
#define NEG_INV -28.853900817779268f    /* -1/(EPS*ln2)  */

__device__ __forceinline__ float4 ld4(const float* p) { return *(const float4*)p; }
__device__ __forceinline__ void   st4(float* p, float4 v) { *(float4*)p = v; }

// One fused step, absolute LDS coords. P holds u_k on entry, u_{k+1} on exit.
// Q is scratch (h-sums, then rcp-h-sums). Halo values at out-of-image
// positions are computed AT the clamped position (edge blocks, scalar path)
// so replicate-pad stays exact recursively.
template<int B_, bool LAST, bool E_IMG, bool WRITEU>
__device__ __forceinline__ void one_step(
    float* __restrict__ P, float* __restrict__ Q,
    int r0, int c0, int tid, bool edge,
    float* __restrict__ uog, const float* __restrict__ imgb,
    float4 (&sk)[2])
{
    constexpr int BC0 = (B_ == 5) ? 0 : 4;            // first col-group
    constexpr int BCL = ((71 + B_) >> 2) << 2;        // last col-group
    constexpr int NG  = (BCL - BC0) / 4 + 1;          // groups per row
    constexpr int RA0 = RO - 1 - B_;                  // phase A rows [RA0,RA1)
    constexpr int NRA = TH + 2 + 2 * B_;
    constexpr int RB0 = RO - B_;                      // phase B rows [RB0,RB1)
    constexpr int NRB = TH + 2 * B_;

    // hoist e = -C1*log2(u_k) before P is overwritten in phase B
    float4 e[2];
    if constexpr (!E_IMG) {
        #pragma unroll
        for (int j = 0; j < 2; ++j) {
            int gi = j * 256 + tid;
            int tr = RO + (gi >> 4), bc = CO + (gi & 15) * 4;
            float4 u = ld4(P + tr * ST + bc);
            e[j].x = -C1 * log2_f(u.x); e[j].y = -C1 * log2_f(u.y);
            e[j].z = -C1 * log2_f(u.z); e[j].w = -C1 * log2_f(u.w);
        }
    }

    // phase A: Q[r][c] = P[r][c-1]+P[r][c]+P[r][c+1]  (centered h-sums)
    for (int gi = tid; gi < NRA * NG; gi += 256) {
        int rr = gi / NG;
        int bc = BC0 + (gi - rr * NG) * 4;
        const float* row = P + (RA0 + rr) * ST;
        float4 q = ld4(row + bc);
        float pm1 = row[bc > 0 ? bc - 1 : 0];
        float p4  = row[bc + 4];
        float4 o;
        o.x = pm1 + q.x + q.y; o.y = q.x + q.y + q.z;
        o.z = q.y + q.z + q.w; o.w = q.z + q.w + p4;
        st4(Q + (RA0 + rr) * ST + bc, o);
    }
    __syncthreads();

    // phase B: P[r][c] = (Q[r-1][c]+Q[r][c]+Q[r+1][c]) / 9   (u_{k+1})
    if (!edge) {
        for (int gi = tid; gi < NRB * NG; gi += 256) {
            int rr = gi / NG;
            int bc = BC0 + (gi - rr * NG) * 4;
            int r = RB0 + rr;
            const float* h = Q + (r - 1) * ST + bc;
            float4 t = ld4(h), m = ld4(h + ST), b = ld4(h + 2 * ST);
            float4 u;
            u.x = (t.x + m.x + b.x) * (1.0f / 9.0f);
            u.y = (t.y + m.y + b.y) * (1.0f / 9.0f);
            u.z = (t.z + m.z + b.z) * (1.0f / 9.0f);
            u.w = (t.w + m.w + b.w) * (1.0f / 9.0f);
            st4(P + r * ST + bc, u);
            if constexpr (LAST && WRITEU) {
                if (r >= RO && r < RO + TH && bc >= CO && bc < CO + TW)
                    *(float4*)(uog + (size_t)(r0 + r - RO) * WW + (c0 + bc - CO)) = u;
            }
        }
    } else {
        constexpr int WID = TW + 2 * B_;
        for (int i = tid; i < NRB * WID; i += 256) {
            int rr = i / WID;
            int c  = (CO - B_) + (i - rr * WID);
            int r  = RB0 + rr;
            int gr = r0 + r - RO, gc = c0 + c - CO;
            int rcl = min(max(gr, 0), HH - 1) - r0 + RO;
            int ccl = min(max(gc, 0), WW - 1) - c0 + CO;
            float u = (Q[(rcl - 1) * ST + ccl] + Q[rcl * ST + ccl] + Q[(rcl + 1) * ST + ccl]) * (1.0f / 9.0f);
            P[r * ST + c] = u;
            if constexpr (LAST && WRITEU) {
                if (r >= RO && r < RO + TH && c >= CO && c < CO + TW)
                    uog[(size_t)gr * WW + gc] = u;
            }
        }
    }
    __syncthreads();

    // phase C: Q[r][c] = rcp(P[r][c-1])+rcp(P[r][c])+rcp(P[r][c+1]),
    //          rows [RO-1, RO+TH+1), cols [CO, CO+TW)
    for (int gi = tid; gi < (TH + 2) * 16; gi += 256) {
        int rr = gi >> 4;
        int bc = CO + (gi & 15) * 4;
        const float* row = P + (RO - 1 + rr) * ST;
        float4 q = ld4(row + bc);
        float pm1 = row[bc - 1], p4 = row[bc + 4];
        float a0 = rcp_f(pm1), a1 = rcp_f(q.x), a2 = rcp_f(q.y),
              a3 = rcp_f(q.z), a4 = rcp_f(q.w), a5 = rcp_f(p4);
        float4 o;
        o.x = a0 + a1 + a2; o.y = a1 + a2 + a3;
        o.z = a2 + a3 + a4; o.w = a3 + a4 + a5;
        st4(Q + (RO - 1 + rr) * ST + bc, o);
    }
    __syncthreads();

    // phase D: dilate v-sum, log, clip, skel accumulate
    #pragma unroll
    for (int j = 0; j < 2; ++j) {
        int gi = j * 256 + tid;
        int tr = RO + (gi >> 4), bc = CO + (gi & 15) * 4;
        const float* h = Q + (tr - 1) * ST + bc;
        float4 t = ld4(h), m = ld4(h + ST), b = ld4(h + 2 * ST);
        float4 d;
        d.x = fminf(fmaxf(C1 * (log2_f(t.x + m.x + b.x) - LOG2_9), 0.0f), 1.0f);
        d.y = fminf(fmaxf(C1 * (log2_f(t.y + m.y + b.y) - LOG2_9), 0.0f), 1.0f);
        d.z = fminf(fmaxf(C1 * (log2_f(t.z + m.z + b.z) - LOG2_9), 0.0f), 1.0f);
        d.w = fminf(fmaxf(C1 * (log2_f(t.w + m.w + b.w) - LOG2_9), 0.0f), 1.0f);
        float4 ee;
        if constexpr (E_IMG)
            ee = *(const float4*)(imgb + (size_t)(r0 + tr - RO) * WW + (c0 + bc - CO));
        else
            ee = e[j];
        sk[j].x += fmaxf(ee.x - d.x, 0.0f);
        sk[j].y += fmaxf(ee.y - d.y, 0.0f);
        sk[j].z += fmaxf(ee.z - d.z, 0.0f);
        sk[j].w += fmaxf(ee.w - d.w, 0.0f);
    }
    __syncthreads();
}

template<int B_, int REMAIN, bool E_IMG, bool WRITEU>
struct Chain {
    static __device__ __forceinline__ void run(
        float* P, float* Q, int r0, int c0, int tid, bool edge,
        float* uog, const float* imgb, float4 (&sk)[2])
    {
        one_step<B_, (REMAIN == 1), E_IMG, WRITEU>(P, Q, r0, c0, tid, edge, uog, imgb, sk);
        if constexpr (REMAIN > 1)
            Chain<B_ - 1, REMAIN - 1, false, WRITEU>::run(P, Q, r0, c0, tid, edge, uog, imgb, sk);
    }
};

template<bool FIRST, int NSTEP, bool WRITEU>
__global__ __launch_bounds__(256, 5)
void sk_fused(const float* __restrict__ u_in, const float* __restrict__ img,
              float* __restrict__ u_out, float* __restrict__ skel)
{
    constexpr int A0 = NSTEP + 1;
    __shared__ __align__(16) float P[RB * ST];   // 15.0 KB
    __shared__ __align__(16) float Q[RB * ST];   // 15.0 KB  (30.0 KB -> 5 blk/CU)

    const int r0  = blockIdx.y * TH;
    const int c0  = blockIdx.x * TW;
    const int tid = threadIdx.x;
    const bool edge = (blockIdx.x == 0) | (blockIdx.x == gridDim.x - 1) |
                      (blockIdx.y == 0) | (blockIdx.y == gridDim.y - 1);
    const size_t boff = (size_t)blockIdx.z * (HH * WW);
    const float* imgb = img + boff;
    float* uog = u_out + boff;
    float* skb = skel + boff;

    // stage u_k at halo A0, clamped replicate (scalar; once per 5 steps)
    {
        constexpr int SH = TH + 2 * A0, SW = TW + 2 * A0;
        const float* uin = u_in + boff;
        for (int i = tid; i < SH * SW; i += 256) {
            int rr = i / SW, cc = i - rr * SW;
            int gr = min(max(r0 + rr - A0, 0), HH - 1);
            int gc = min(max(c0 + cc - A0, 0), WW - 1);
            float v;
            if constexpr (FIRST) v = exp2_f(imgb[gr * WW + gc] * NEG_INV);
            else                 v = uin[gr * WW + gc];
            P[(RO - A0 + rr) * ST + (CO - A0 + cc)] = v;
        }
    }
    __syncthreads();

    float4 sk[2];
    sk[0] = make_float4(0.f, 0.f, 0.f, 0.f);
    sk[1] = make_float4(0.f, 0.f, 0.f, 0.f);

    Chain<NSTEP, NSTEP, FIRST, WRITEU>::run(P, Q, r0, c0, tid, edge, uog, imgb, sk);

    #pragma unroll
    for (int j = 0; j < 2; ++j) {
        int gi = j * 256 + tid;
        int tr = RO + (gi >> 4), bc = CO + (gi & 15) * 4;
        float* sp = skb + (size_t)(r0 + tr - RO) * WW + (c0 + bc - CO);
        if constexpr (FIRST) {
            *(float4*)sp = sk[j];
        } else {
            float4 old = *(const float4*)sp;
            old.x += sk[j].x; old.y += sk[j].y; old.z += sk[j].z; old.w += sk[j].w;
            *(float4*)sp = old;
        }
    }
}

extern "C" void kernel_launch(void* const* d_in, const int* in_sizes, int n_in,
                              void* d_out, int out_size, void* d_ws, size_t ws_size,
                              hipStream_t stream) {
    const float* img = (const float*)d_in[0];
    float* skel = (float*)d_out;
    const size_t N = (size_t)NB * HH * WW;
    float* ua = (float*)d_ws;
    float* ub = ua + N;                       // 16.8 MB of ws used

    dim3 grid(WW / TW, HH / TH, NB);          // (8,16,8) = 1024 blocks

    // steps 0..4 (e_0 = img exactly), writes u5
    sk_fused<true, 5, true><<<grid, 256, 0, stream>>>(nullptr, img, ua, skel);

    // steps 5..49 in 9 kernels of 5
    float* uin = ua; float* uout = ub;
    for (int t = 0; t < 9; ++t) {
        sk_fused<false, 5, true><<<grid, 256, 0, stream>>>(uin, img, uout, skel);
        float* tmp = uin; uin = uout; uout = tmp;
    }

    // step 50 (no u write needed)
    sk_fused<false, 1, false><<<grid, 256, 0, stream>>>(uin, img, uout, skel);
}